// Round 7
// baseline (281.855 us; speedup 1.0000x reference)
//
#include <hip/hip_runtime.h>
#include <hip/hip_bf16.h>

// loss = mean_b (out_b - label_b)^2
// out_b = sqrt(s_ab) / (s_aa^(1/4) * s_bb^(1/4)),  s_xy = ||X Y^T||_F^2.
//
// 8 WGs per batch (512 thr, 8 waves), stack = 256 rows, dbuf 2x32KB = 64KB
// -> exactly 2 blocks/CU (the overlap R1 lacked). Types:
//   ty0/ty1: stack = A;        waves: xu = (ty&1)*2 + (wv>>2), yu = wv&3
//            -> full 4x4 AA unit grid across the two WGs, w=1 (both orders)
//   ty2/ty3: same for B (BB)
//   ty4..7:  stack = {A-half i, B-half j}, i=(ty>>1)&1, j=ty&1; waves take
//            64x32 half-tiles: x = wv>>2, y64 = (wv>>1)&1, y32 = wv&1
// LDS recipe is R1/R2's measured-zero-conflict pattern VERBATIM:
//   row-major [row][64] bf16 (128B row stride), 8B subchunk u stored at
//   slot u^(row&15); frag = 2x b64 at off / off^4 with u0 = (ks*2+kh)*2.

typedef short short8  __attribute__((ext_vector_type(8)));
typedef short short4_ __attribute__((ext_vector_type(4)));
typedef float f32x16  __attribute__((ext_vector_type(16)));

constexpr int S = 256, D = 384, BK = 64, NCH = 6;

__device__ __forceinline__ short bf16_of(float f){
    __hip_bfloat16 h = __float2bfloat16(f);   // RNE
    short s; __builtin_memcpy(&s, &h, 2); return s;
}

// R2-verbatim fragment read: two b64 at swizzled slots (measured 0-conflict).
__device__ __forceinline__ short8 frag_read(const short* L, int row, int ks, int lane) {
    const int u0 = (ks * 2 + (lane >> 5)) * 2;
    const int x  = row & 15;
    const int rb = row * BK;
    short8 f;
    *(short4_*)&f     = *(const short4_*)&L[rb + ((u0    ) ^ x) * 4];
    ((short4_*)&f)[1] = *(const short4_*)&L[rb + ((u0 + 1) ^ x) * 4];
    return f;
}

#define MFMA(a,b,c) __builtin_amdgcn_mfma_f32_32x32x16_bf16(a, b, c, 0, 0, 0)

__global__ __launch_bounds__(512, 4)
void gram(const float* __restrict__ A, const float* __restrict__ B,
          float* __restrict__ ws)
{
    __shared__ short lds[2][S * BK];   // 2 x 32 KiB

    // bid&7 = XCD; all 8 WGs of a batch share one XCD (L2 reuse).
    const int bid = blockIdx.x;
    const int xcd = bid & 7;
    const int idx = bid >> 3;          // 0..127
    const int bl  = idx >> 3;          // 0..15
    const int ty  = idx & 7;
    const int batch = (xcd << 4) + bl;

    const float* Ab = A + (size_t)batch * S * D;
    const float* Bb = B + (size_t)batch * S * D;

    const int tid  = threadIdx.x;
    const int lane = tid & 63;
    const int wv   = tid >> 6;         // 0..7
    const int l31  = lane & 31;
    const bool isab = (ty >= 4);

    // ---- staging map (R2-verbatim pattern, 256 rows x 512 thr) ----
    // tr = tid>>4 (0..31), u = tid&15; rows tr + 32i, i = 0..7.
    const int tr = tid >> 4;
    const int u  = tid & 15;
    const int wb = tr * BK + ((u ^ (tr & 15)) << 2);   // +i*2048 per group
    const float* p_lo;   // source of stack rows   0..127
    const float* p_hi;   // source of stack rows 128..255
    if (!isab) {
        const float* M = (ty < 2) ? Ab : Bb;
        p_lo = M + (size_t)tr * D;
        p_hi = M + (size_t)(128 + tr) * D;
    } else {
        p_lo = Ab + (size_t)(((ty >> 1) & 1) * 128 + tr) * D;
        p_hi = Bb + (size_t)(((ty     ) & 1) * 128 + tr) * D;
    }
    p_lo += u * 4; p_hi += u * 4;

    // ---- per-wave job rows ----
    int xbase, ybase;
    if (!isab) { xbase = ((ty & 1) * 2 + (wv >> 2)) * 64; ybase = (wv & 3) * 64; }
    else       { xbase = (wv >> 2) * 64;
                 ybase = 128 + ((wv >> 1) & 1) * 64 + (wv & 1) * 32; }
    const int xr0 = xbase + l31, xr1 = xbase + 32 + l31;
    const int yr0 = ybase + l31, yr1 = ybase + 32 + l31;  // yr1 unused if isab

    f32x16 a00 = {}, a01 = {}, a10 = {}, a11 = {};  // AB leaves a01,a11 at 0
    float4 v[8];

#define LOADS(kc) { \
    _Pragma("unroll") for (int i = 0; i < 8; ++i) { \
        const float* p = (i < 4) ? (p_lo + (size_t)i * 32 * D) \
                                 : (p_hi + (size_t)(i - 4) * 32 * D); \
        v[i] = *(const float4*)(p + (kc) * BK); } }

#define WRITES(bs) { short* Lb = lds[bs]; \
    _Pragma("unroll") for (int i = 0; i < 8; ++i) { \
        short4_ pk; \
        pk[0] = bf16_of(v[i].x); pk[1] = bf16_of(v[i].y); \
        pk[2] = bf16_of(v[i].z); pk[3] = bf16_of(v[i].w); \
        *(short4_*)&Lb[wb + i * 2048] = pk; } }

#define COMPUTE(bs) { const short* Lb = lds[bs]; \
    if (!isab) { \
        _Pragma("unroll") for (int ks = 0; ks < 4; ++ks) { \
            short8 x0 = frag_read(Lb, xr0, ks, lane); \
            short8 x1 = frag_read(Lb, xr1, ks, lane); \
            short8 y0 = frag_read(Lb, yr0, ks, lane); \
            short8 y1 = frag_read(Lb, yr1, ks, lane); \
            a00 = MFMA(x0, y0, a00); a01 = MFMA(x0, y1, a01); \
            a10 = MFMA(x1, y0, a10); a11 = MFMA(x1, y1, a11); } \
    } else { \
        _Pragma("unroll") for (int ks = 0; ks < 4; ++ks) { \
            short8 x0 = frag_read(Lb, xr0, ks, lane); \
            short8 x1 = frag_read(Lb, xr1, ks, lane); \
            short8 y0 = frag_read(Lb, yr0, ks, lane); \
            a00 = MFMA(x0, y0, a00); \
            a10 = MFMA(x1, y0, a10); } } }

    // ---- main loop: issue next chunk's loads early (T14), dbuf LDS ----
    LOADS(0); WRITES(0); __syncthreads();
    for (int c = 0; c < NCH; ++c) {
        if (c + 1 < NCH) LOADS(c + 1);
        COMPUTE(c & 1);
        if (c + 1 < NCH) WRITES((c + 1) & 1);
        __syncthreads();
    }

    // ---- square-accumulate -> one scalar per WG (a01/a11 = 0 for AB) ----
    float sum = 0.f;
    #pragma unroll
    for (int e = 0; e < 16; ++e)
        sum += a00[e]*a00[e] + a01[e]*a01[e] + a10[e]*a10[e] + a11[e]*a11[e];
    #pragma unroll
    for (int o = 32; o > 0; o >>= 1) sum += __shfl_xor(sum, o, 64);
    float* red = (float*)lds;      // safe: barrier after last COMPUTE
    if (lane == 0) red[wv] = sum;
    __syncthreads();
    if (tid == 0) {
        float t = 0.f;
        #pragma unroll
        for (int k = 0; k < 8; ++k) t += red[k];
        ws[bid] = t;
    }
}

__global__ void finalize(const float* __restrict__ ws,
                         const float* __restrict__ labels,
                         float* __restrict__ out)
{
    __shared__ float red[128];
    const int b = threadIdx.x;             // one thread per batch
    const int xc = b >> 4, bl = b & 15;
    #define W(t) ws[((((bl << 3) | (t)) << 3) | xc)]
    const float saa = W(0) + W(1);
    const float sbb = W(2) + W(3);
    const float sab = W(4) + W(5) + W(6) + W(7);
    #undef W
    const float outb = sqrtf(sab) / (sqrtf(sqrtf(saa)) * sqrtf(sqrtf(sbb)));
    const float d    = outb - labels[b];
    red[b] = d * d * (1.0f / 128.0f);
    __syncthreads();
    for (int off = 64; off > 0; off >>= 1) {
        if (b < off) red[b] += red[b + off];
        __syncthreads();
    }
    if (b == 0) out[0] = red[0];
}

extern "C" void kernel_launch(void* const* d_in, const int* in_sizes, int n_in,
                              void* d_out, int out_size, void* d_ws, size_t ws_size,
                              hipStream_t stream)
{
    const float* A      = (const float*)d_in[0];
    const float* B      = (const float*)d_in[1];
    const float* labels = (const float*)d_in[2];
    float* ws = (float*)d_ws;   // 1024 floats, all written every launch

    gram<<<dim3(1024), dim3(512), 0, stream>>>(A, B, ws);
    finalize<<<dim3(1), dim3(128), 0, stream>>>(ws, labels, (float*)d_out);
}

// Round 8
// 41.213 us; speedup vs baseline: 6.8389x; 6.8389x over previous
//
#include <hip/hip_runtime.h>
#include <hip/hip_bf16.h>

// loss = mean_b (out_b - label_b)^2
// out_b = sqrt(s_ab) / (s_aa^(1/4) * s_bb^(1/4)),  s_xy = ||X Y^T||_F^2.
//
// 12 WGs/batch (512 thr, 8 waves), UNIFORM 32x64 tile per wave (acc = 32
// VGPR -> no spill; R7's 281us disaster was launch_bounds(512,4) + ~136
// VGPR need -> scratch). dbuf 2x32KB = 64KB -> 2 blocks/CU.
//   ty 0..3  : stack = A (256 rows); wave (xs,ys) = (2*ty + wv>>2, wv&3)
//              -> AA strips 32x64, full 8x4 grid over 4 WGs, w=1
//   ty 4..7  : same with B (BB)
//   ty 8..11 : stack = A-half h || B-half g, (h,g) = ((ty-8)>>1, (ty-8)&1);
//              wave: X strip wv>>1 (A side), Y strip wv&1 (B side)
// LDS recipe R2-verbatim (measured 0-conflict): row-major [row][64] bf16,
// 8B subchunk u at slot u^(row&15), b64-pair frag reads, b64 stage writes.

typedef short short8  __attribute__((ext_vector_type(8)));
typedef short short4_ __attribute__((ext_vector_type(4)));
typedef float f32x16  __attribute__((ext_vector_type(16)));

constexpr int S = 256, D = 384, BK = 64, NCH = 6;

__device__ __forceinline__ short bf16_of(float f){
    __hip_bfloat16 h = __float2bfloat16(f);   // RNE
    short s; __builtin_memcpy(&s, &h, 2); return s;
}

// R2-verbatim fragment read: two b64 at swizzled slots.
__device__ __forceinline__ short8 frag_read(const short* L, int row, int ks, int lane) {
    const int u0 = (ks * 2 + (lane >> 5)) * 2;
    const int x  = row & 15;
    const int rb = row * BK;
    short8 f;
    *(short4_*)&f     = *(const short4_*)&L[rb + ((u0    ) ^ x) * 4];
    ((short4_*)&f)[1] = *(const short4_*)&L[rb + ((u0 + 1) ^ x) * 4];
    return f;
}

#define MFMA(a,b,c) __builtin_amdgcn_mfma_f32_32x32x16_bf16(a, b, c, 0, 0, 0)

__global__ __launch_bounds__(512, 4)
void gram(const float* __restrict__ A, const float* __restrict__ B,
          float* __restrict__ ws)
{
    __shared__ short lds[2][S * BK];   // 2 x 32 KiB

    // bid&7 = XCD; all 12 WGs of a batch share one XCD (L2 reuse).
    const int bid = blockIdx.x;
    const int xcd = bid & 7;
    const int idx = bid >> 3;          // 0..191
    const int bl  = idx / 12;          // 0..15
    const int ty  = idx - bl * 12;     // 0..11
    const int batch = (xcd << 4) + bl;

    const float* Ab = A + (size_t)batch * S * D;
    const float* Bb = B + (size_t)batch * S * D;

    const int tid  = threadIdx.x;
    const int lane = tid & 63;
    const int wv   = tid >> 6;         // 0..7
    const int l31  = lane & 31;

    // ---- staging map (R2-verbatim): tr = tid>>4, u = tid&15; rows tr+32i ----
    const int tr = tid >> 4;           // 0..31
    const int u  = tid & 15;
    const int wb = tr * BK + ((u ^ (tr & 15)) << 2);   // +i*2048 per group
    const float* p_lo;   // stack rows   0..127
    const float* p_hi;   // stack rows 128..255
    if (ty < 8) {
        const float* M = (ty < 4) ? Ab : Bb;
        p_lo = M + (size_t)tr * D;
        p_hi = M + (size_t)(128 + tr) * D;
    } else {
        const int h = (ty - 8) >> 1, g = (ty - 8) & 1;
        p_lo = Ab + (size_t)(h * 128 + tr) * D;
        p_hi = Bb + (size_t)(g * 128 + tr) * D;
    }
    p_lo += u * 4; p_hi += u * 4;

    // ---- per-wave job: X strip (32 rows) x Y strip (64 rows) ----
    int xbase, ybase;
    if (ty < 8) {
        const int q = ty & 3;
        xbase = (q * 2 + (wv >> 2)) * 32;      // 0..224
        ybase = (wv & 3) * 64;                 // 0..192
    } else {
        xbase = (wv >> 1) * 32;                // 0..96 within A half
        ybase = 128 + (wv & 1) * 64;           // B half in stack
    }
    const int xr  = xbase + l31;
    const int yr0 = ybase + l31, yr1 = ybase + 32 + l31;

    f32x16 a0 = {}, a1 = {};           // 32 VGPRs of accumulator
    float4 v[8];

#define LOADS(kc) { \
    _Pragma("unroll") for (int i = 0; i < 8; ++i) { \
        const float* p = (i < 4) ? (p_lo + (size_t)i * 32 * D) \
                                 : (p_hi + (size_t)(i - 4) * 32 * D); \
        v[i] = *(const float4*)(p + (kc) * BK); } }

#define WRITES(bs) { short* Lb = lds[bs]; \
    _Pragma("unroll") for (int i = 0; i < 8; ++i) { \
        short4_ pk; \
        pk[0] = bf16_of(v[i].x); pk[1] = bf16_of(v[i].y); \
        pk[2] = bf16_of(v[i].z); pk[3] = bf16_of(v[i].w); \
        *(short4_*)&Lb[wb + i * 2048] = pk; } }

#define COMPUTE(bs) { const short* Lb = lds[bs]; \
    _Pragma("unroll") for (int ks = 0; ks < 4; ++ks) { \
        short8 x0 = frag_read(Lb, xr,  ks, lane); \
        short8 y0 = frag_read(Lb, yr0, ks, lane); \
        short8 y1 = frag_read(Lb, yr1, ks, lane); \
        a0 = MFMA(x0, y0, a0); \
        a1 = MFMA(x0, y1, a1); } }

    // ---- main loop: issue next chunk's loads early (T14), dbuf LDS ----
    LOADS(0); WRITES(0); __syncthreads();
    for (int c = 0; c < NCH; ++c) {
        if (c + 1 < NCH) LOADS(c + 1);
        COMPUTE(c & 1);
        if (c + 1 < NCH) WRITES((c + 1) & 1);
        __syncthreads();
    }

    // ---- square-accumulate -> one scalar per WG ----
    float sum = 0.f;
    #pragma unroll
    for (int e = 0; e < 16; ++e) sum += a0[e] * a0[e] + a1[e] * a1[e];
    #pragma unroll
    for (int o = 32; o > 0; o >>= 1) sum += __shfl_xor(sum, o, 64);
    float* red = (float*)lds;      // safe: barrier after last COMPUTE
    if (lane == 0) red[wv] = sum;
    __syncthreads();
    if (tid == 0) {
        float t = 0.f;
        #pragma unroll
        for (int k = 0; k < 8; ++k) t += red[k];
        ws[bid] = t;
    }
}

__global__ void finalize(const float* __restrict__ ws,
                         const float* __restrict__ labels,
                         float* __restrict__ out)
{
    __shared__ float red[128];
    const int b = threadIdx.x;             // one thread per batch
    const int xc = b >> 4, bl = b & 15;
    #define W(t) ws[(((bl * 12 + (t)) << 3) | xc)]
    const float saa = W(0) + W(1) + W(2)  + W(3);
    const float sbb = W(4) + W(5) + W(6)  + W(7);
    const float sab = W(8) + W(9) + W(10) + W(11);
    #undef W
    const float outb = sqrtf(sab) / (sqrtf(sqrtf(saa)) * sqrtf(sqrtf(sbb)));
    const float d    = outb - labels[b];
    red[b] = d * d * (1.0f / 128.0f);
    __syncthreads();
    for (int off = 64; off > 0; off >>= 1) {
        if (b < off) red[b] += red[b + off];
        __syncthreads();
    }
    if (b == 0) out[0] = red[0];
}

extern "C" void kernel_launch(void* const* d_in, const int* in_sizes, int n_in,
                              void* d_out, int out_size, void* d_ws, size_t ws_size,
                              hipStream_t stream)
{
    const float* A      = (const float*)d_in[0];
    const float* B      = (const float*)d_in[1];
    const float* labels = (const float*)d_in[2];
    float* ws = (float*)d_ws;   // 1536 floats, all written every launch

    gram<<<dim3(1536), dim3(512), 0, stream>>>(A, B, ws);
    finalize<<<dim3(1), dim3(128), 0, stream>>>(ws, labels, (float*)d_out);
}

// Round 9
// 36.771 us; speedup vs baseline: 7.6652x; 1.1208x over previous
//
#include <hip/hip_runtime.h>
#include <hip/hip_bf16.h>

// loss = mean_b (out_b - label_b)^2
// out_b = sqrt(s_ab) / (s_aa^(1/4) * s_bb^(1/4)),  s_xy = ||X Y^T||_F^2.
//
// 10 WGs/batch (256 thr, 4 waves). Each WG = one 128x128 site of one
// product; 4 waves = 2x2 quadrants of 64x64 (4 frags -> 4 MFMAs = 1KB
// LDS-read per MFMA, the binding pipe of rounds 1-8). Sites:
//   ty0..2: AA (0,0)w1 (0,1)w2 (1,1)w1      (upper-tri, transpose weighted)
//   ty3..5: BB same
//   ty6..9: AB (i,j) all w1
// All WGs stage a uniform 256-row stack (two 128-row blocks), dbuf
// 2x32KB = 64KB -> 2 blocks/CU for cross-block overlap.
// LDS geometry is the twice-measured-zero-conflict recipe, character-level:
//   write: tr=tid>>4 (0..15), u=tid&15, b64 at  tr*64 + ((u^tr)<<2) hw,
//          rows tr+16i (row&15 == tr invariant)
//   read:  frag_read = 2x b64, u0=(ks*2+kh)*2, slot u ^ (row&15),
//          row bases multiples of 64 (+32), +l31.

typedef short short8  __attribute__((ext_vector_type(8)));
typedef short short4_ __attribute__((ext_vector_type(4)));
typedef float f32x16  __attribute__((ext_vector_type(16)));

constexpr int S = 256, D = 384, BK = 64, NCH = 6;

__device__ __forceinline__ short bf16_of(float f){
    __hip_bfloat16 h = __float2bfloat16(f);   // RNE
    short s; __builtin_memcpy(&s, &h, 2); return s;
}

// Measured-zero-conflict fragment read (rounds 2/3 profile): two b64.
__device__ __forceinline__ short8 frag_read(const short* L, int row, int ks, int lane) {
    const int u0 = (ks * 2 + (lane >> 5)) * 2;
    const int x  = row & 15;
    const int rb = row * BK;
    short8 f;
    *(short4_*)&f     = *(const short4_*)&L[rb + ((u0    ) ^ x) * 4];
    ((short4_*)&f)[1] = *(const short4_*)&L[rb + ((u0 + 1) ^ x) * 4];
    return f;
}

#define MFMA(a,b,c) __builtin_amdgcn_mfma_f32_32x32x16_bf16(a, b, c, 0, 0, 0)

__global__ __launch_bounds__(256, 2)
void gram(const float* __restrict__ A, const float* __restrict__ B,
          float* __restrict__ ws)
{
    __shared__ short lds[2][S * BK];   // 2 x 32 KiB -> 2 blocks/CU

    // bid&7 = XCD; all 10 WGs of a batch share one XCD (L2 reuse).
    const int bid = blockIdx.x;
    const int xcd = bid & 7;
    const int idx = bid >> 3;          // 0..159
    const int bl  = idx / 10;          // 0..15
    const int ty  = idx - bl * 10;     // 0..9
    const int batch = (xcd << 4) + bl;

    const float* Ab = A + (size_t)batch * S * D;
    const float* Bb = B + (size_t)batch * S * D;

    // ---- site params ----
    int SX, SY; float w;
    const float *p_lo, *p_hi;          // stack rows 0..127 / 128..255
    if (ty < 6) {
        const float* M = (ty < 3) ? Ab : Bb;
        const int k = (ty < 3) ? ty : ty - 3;
        SX = (k == 2); SY = (k != 0);
        w  = (k == 1) ? 2.f : 1.f;
        p_lo = M; p_hi = M + (size_t)128 * D;
    } else {
        const int k = ty - 6;
        SX = 0; SY = 1; w = 1.f;
        p_lo = Ab + (size_t)(k >> 1) * 128 * D;
        p_hi = Bb + (size_t)(k & 1) * 128 * D;
    }

    const int tid  = threadIdx.x;
    const int lane = tid & 63;
    const int wv   = tid >> 6;         // 0..3
    const int l31  = lane & 31;

    // ---- staging map (verbatim): tr 0..15, u 0..15, rows tr+16i ----
    const int tr = tid >> 4;
    const int u  = tid & 15;
    const int wb = tr * BK + ((u ^ tr) << 2);          // + i*16*BK per group
    const float* gl = p_lo + (size_t)tr * D + u * 4;   // rows  tr+16i, i<8
    const float* gh = p_hi + (size_t)tr * D + u * 4;   // rows  tr+16(i-8)

    // ---- wave quadrant of the 128x128 site ----
    const int xbase = SX * 128 + (wv >> 1) * 64;
    const int ybase = SY * 128 + (wv & 1) * 64;
    const int xr0 = xbase + l31, xr1 = xbase + 32 + l31;
    const int yr0 = ybase + l31, yr1 = ybase + 32 + l31;

    f32x16 a00 = {}, a01 = {}, a10 = {}, a11 = {};
    float4 v[16];

#define LOADS(kc) { \
    _Pragma("unroll") for (int i = 0; i < 8; ++i) \
        v[i]     = *(const float4*)(gl + (size_t)i * 16 * D + (kc) * BK); \
    _Pragma("unroll") for (int i = 0; i < 8; ++i) \
        v[8 + i] = *(const float4*)(gh + (size_t)i * 16 * D + (kc) * BK); }

#define WRITES(bs) { short* Lb = lds[bs]; \
    _Pragma("unroll") for (int i = 0; i < 16; ++i) { \
        short4_ pk; \
        pk[0] = bf16_of(v[i].x); pk[1] = bf16_of(v[i].y); \
        pk[2] = bf16_of(v[i].z); pk[3] = bf16_of(v[i].w); \
        *(short4_*)&Lb[wb + i * 16 * BK] = pk; } }

#define COMPUTE(bs) { const short* Lb = lds[bs]; \
    _Pragma("unroll") for (int ks = 0; ks < 4; ++ks) { \
        short8 x0 = frag_read(Lb, xr0, ks, lane); \
        short8 x1 = frag_read(Lb, xr1, ks, lane); \
        short8 y0 = frag_read(Lb, yr0, ks, lane); \
        short8 y1 = frag_read(Lb, yr1, ks, lane); \
        a00 = MFMA(x0, y0, a00); a01 = MFMA(x0, y1, a01); \
        a10 = MFMA(x1, y0, a10); a11 = MFMA(x1, y1, a11); } }

    // ---- main loop: issue next chunk's loads early (T14), dbuf LDS ----
    LOADS(0); WRITES(0); __syncthreads();
    for (int c = 0; c < NCH; ++c) {
        if (c + 1 < NCH) LOADS(c + 1);
        COMPUTE(c & 1);
        if (c + 1 < NCH) WRITES((c + 1) & 1);
        __syncthreads();
    }

    // ---- square-accumulate (x site weight) -> one scalar per WG ----
    float sum = 0.f;
    #pragma unroll
    for (int e = 0; e < 16; ++e)
        sum += a00[e]*a00[e] + a01[e]*a01[e] + a10[e]*a10[e] + a11[e]*a11[e];
    sum *= w;
    #pragma unroll
    for (int o = 32; o > 0; o >>= 1) sum += __shfl_xor(sum, o, 64);
    float* red = (float*)lds;      // safe: barrier after last COMPUTE
    if (lane == 0) red[wv] = sum;
    __syncthreads();
    if (tid == 0) ws[bid] = red[0] + red[1] + red[2] + red[3];
}

__global__ void finalize(const float* __restrict__ ws,
                         const float* __restrict__ labels,
                         float* __restrict__ out)
{
    __shared__ float red[128];
    const int b = threadIdx.x;             // one thread per batch
    const int xc = b >> 4, bl = b & 15;
    #define W(t) ws[(((bl * 10 + (t)) << 3) | xc)]
    const float saa = W(0) + W(1) + W(2);
    const float sbb = W(3) + W(4) + W(5);
    const float sab = W(6) + W(7) + W(8) + W(9);
    #undef W
    const float outb = sqrtf(sab) / (sqrtf(sqrtf(saa)) * sqrtf(sqrtf(sbb)));
    const float d    = outb - labels[b];
    red[b] = d * d * (1.0f / 128.0f);
    __syncthreads();
    for (int off = 64; off > 0; off >>= 1) {
        if (b < off) red[b] += red[b + off];
        __syncthreads();
    }
    if (b == 0) out[0] = red[0];
}

extern "C" void kernel_launch(void* const* d_in, const int* in_sizes, int n_in,
                              void* d_out, int out_size, void* d_ws, size_t ws_size,
                              hipStream_t stream)
{
    const float* A      = (const float*)d_in[0];
    const float* B      = (const float*)d_in[1];
    const float* labels = (const float*)d_in[2];
    float* ws = (float*)d_ws;   // 1280 floats, all written every launch

    gram<<<dim3(1280), dim3(256), 0, stream>>>(A, B, ws);
    finalize<<<dim3(1), dim3(128), 0, stream>>>(ws, labels, (float*)d_out);
}

// Round 10
// 33.855 us; speedup vs baseline: 8.3255x; 1.0861x over previous
//
#include <hip/hip_runtime.h>
#include <hip/hip_bf16.h>

// loss = mean_b (out_b - label_b)^2
// out_b = sqrt(s_ab) / (s_aa^(1/4) * s_bb^(1/4)),  s_xy = ||X Y^T||_F^2.
//
// 4 WGs/batch (512 thr, 8 waves), grid 512 = 2 clean rounds over 256 CUs:
//   ty0: AA — stack = A (256 rows); wave (r=(wv>>1)*64, c1=(wv&1)*128):
//        TWO 64x64 jobs (r,c1),(r,c1+64) sharing x-frags -> 1.5 b64/MFMA
//   ty1: BB — same with B
//   ty2/3: AB-L/R — stack = A(256) || B-half(128); one 64x64 job/wave
// acc = 128 VGPR -> 8 waves/CU (VGPR-capped anyway; LDS dbuf 2x48KB).
// One barrier per chunk; LOADS(c+1) issued early (T14); COMPUTE(c) and
// WRITES(c+1) share the barrier-free region (different dbuf halves).
// LDS recipe = measured-zero-conflict geometry (R2/R9 profiles) with
// row % 16 == tr % 16 invariant: write b64 at slot u^(tr&15), frag =
// 2x b64 at u0=(ks*2+kh)*2 slots u0^(row&15), row bases = 0 mod 32.

typedef short short8  __attribute__((ext_vector_type(8)));
typedef short short4_ __attribute__((ext_vector_type(4)));
typedef float f32x16  __attribute__((ext_vector_type(16)));

constexpr int S = 256, D = 384, BK = 64, NCH = 6;

__device__ __forceinline__ short bf16_of(float f){
    __hip_bfloat16 h = __float2bfloat16(f);   // RNE
    short s; __builtin_memcpy(&s, &h, 2); return s;
}

__device__ __forceinline__ short8 frag_read(const short* L, int row, int ks, int lane) {
    const int u0 = (ks * 2 + (lane >> 5)) * 2;
    const int x  = row & 15;
    const int rb = row * BK;
    short8 f;
    *(short4_*)&f     = *(const short4_*)&L[rb + ((u0    ) ^ x) * 4];
    ((short4_*)&f)[1] = *(const short4_*)&L[rb + ((u0 + 1) ^ x) * 4];
    return f;
}

#define MFMA(a,b,c) __builtin_amdgcn_mfma_f32_32x32x16_bf16(a, b, c, 0, 0, 0)

__global__ __launch_bounds__(512, 2)
void gram(const float* __restrict__ A, const float* __restrict__ B,
          float* __restrict__ ws)
{
    __shared__ short lds[2][384 * BK];   // 2 x 48 KiB

    // bid&7 = XCD; the 4 WGs of a batch share one XCD (L2 reuse).
    const int bid = blockIdx.x;
    const int xcd = bid & 7;
    const int idx = bid >> 3;          // 0..63
    const int bl  = idx >> 2;          // 0..15
    const int ty  = idx & 3;           // 0:AA 1:BB 2:AB-L 3:AB-R
    const int batch = (xcd << 4) + bl;

    const float* Abase = A + (size_t)batch * S * D;
    const float* Bbase = B + (size_t)batch * S * D;

    const int tid  = threadIdx.x;
    const int lane = tid & 63;
    const int wv   = tid >> 6;         // 0..7
    const int l31  = lane & 31;
    const bool ab  = (ty >= 2);
    const int nst  = ab ? 12 : 8;      // 32-row staging groups

    // ---- staging map: tr = tid>>4 (0..31), u = tid&15; rows tr + 32i ----
    const int tr = tid >> 4;
    const int u  = tid & 15;
    const int wb = tr * BK + ((u ^ (tr & 15)) << 2);   // + i*2048 per group
    const float* pA = ((ty == 1) ? Bbase : Abase) + (size_t)tr * D + u * 4;
    const float* pB = Bbase + (size_t)(((ty & 1) * 128) + tr) * D + u * 4;

    // ---- per-wave jobs ----
    const int r  = (wv >> 1) * 64;
    const int c1 = ab ? (256 + (wv & 1) * 64) : ((wv & 1) * 128);
    const int c2 = c1 + 64;                       // used only if !ab
    const int xr0 = r  + l31, xr1 = r  + 32 + l31;
    const int yr0 = c1 + l31, yr1 = c1 + 32 + l31;
    const int yr2 = c2 + l31, yr3 = c2 + 32 + l31;

    f32x16 a0 = {}, a1 = {}, a2 = {}, a3 = {};
    f32x16 a4 = {}, a5 = {}, a6 = {}, a7 = {};    // zero for AB waves
    float4 v[12];

#define LOADS(kc) { \
    _Pragma("unroll") for (int i = 0; i < 12; ++i) if (i < nst) { \
        const float* p = (i < 8) ? (pA + (size_t)i * 32 * D) \
                                 : (pB + (size_t)(i - 8) * 32 * D); \
        v[i] = *(const float4*)(p + (kc) * BK); } }

#define WRITES(bs) { short* Lb = lds[bs]; \
    _Pragma("unroll") for (int i = 0; i < 12; ++i) if (i < nst) { \
        short4_ pk; \
        pk[0] = bf16_of(v[i].x); pk[1] = bf16_of(v[i].y); \
        pk[2] = bf16_of(v[i].z); pk[3] = bf16_of(v[i].w); \
        *(short4_*)&Lb[wb + i * 2048] = pk; } }

#define COMPUTE(bs) { const short* Lb = lds[bs]; \
    _Pragma("unroll") for (int ks = 0; ks < 4; ++ks) { \
        short8 x0 = frag_read(Lb, xr0, ks, lane); \
        short8 x1 = frag_read(Lb, xr1, ks, lane); \
        short8 y0 = frag_read(Lb, yr0, ks, lane); \
        short8 y1 = frag_read(Lb, yr1, ks, lane); \
        a0 = MFMA(x0, y0, a0); a1 = MFMA(x0, y1, a1); \
        a2 = MFMA(x1, y0, a2); a3 = MFMA(x1, y1, a3); \
        if (!ab) { \
            short8 y2 = frag_read(Lb, yr2, ks, lane); \
            short8 y3 = frag_read(Lb, yr3, ks, lane); \
            a4 = MFMA(x0, y2, a4); a5 = MFMA(x0, y3, a5); \
            a6 = MFMA(x1, y2, a6); a7 = MFMA(x1, y3, a7); } } }

    // ---- main loop: one barrier per chunk; loads issued early (T14) ----
    LOADS(0); WRITES(0); __syncthreads();
    for (int c = 0; c < NCH; ++c) {
        if (c + 1 < NCH) LOADS(c + 1);
        COMPUTE(c & 1);
        if (c + 1 < NCH) WRITES((c + 1) & 1);
        __syncthreads();
    }

    // ---- square-accumulate -> one scalar per WG ----
    float sum = 0.f;
    #pragma unroll
    for (int e = 0; e < 16; ++e) {
        sum += a0[e]*a0[e] + a1[e]*a1[e] + a2[e]*a2[e] + a3[e]*a3[e];
        sum += a4[e]*a4[e] + a5[e]*a5[e] + a6[e]*a6[e] + a7[e]*a7[e];
    }
    #pragma unroll
    for (int o = 32; o > 0; o >>= 1) sum += __shfl_xor(sum, o, 64);
    float* red = (float*)lds;      // safe: barrier after last COMPUTE
    if (lane == 0) red[wv] = sum;
    __syncthreads();
    if (tid == 0) {
        float t = 0.f;
        #pragma unroll
        for (int k = 0; k < 8; ++k) t += red[k];
        ws[bid] = t;
    }
}

__global__ void finalize(const float* __restrict__ ws,
                         const float* __restrict__ labels,
                         float* __restrict__ out)
{
    __shared__ float red[128];
    const int b = threadIdx.x;             // one thread per batch
    const int xc = b >> 4, bl = b & 15;
    #define W(t) ws[((((bl << 2) | (t)) << 3) | xc)]
    const float saa = W(0);
    const float sbb = W(1);
    const float sab = W(2) + W(3);
    #undef W
    const float outb = sqrtf(sab) / (sqrtf(sqrtf(saa)) * sqrtf(sqrtf(sbb)));
    const float d    = outb - labels[b];
    red[b] = d * d * (1.0f / 128.0f);
    __syncthreads();
    for (int off = 64; off > 0; off >>= 1) {
        if (b < off) red[b] += red[b + off];
        __syncthreads();
    }
    if (b == 0) out[0] = red[0];
}

extern "C" void kernel_launch(void* const* d_in, const int* in_sizes, int n_in,
                              void* d_out, int out_size, void* d_ws, size_t ws_size,
                              hipStream_t stream)
{
    const float* A      = (const float*)d_in[0];
    const float* B      = (const float*)d_in[1];
    const float* labels = (const float*)d_in[2];
    float* ws = (float*)d_ws;   // 512 floats, all written every launch

    gram<<<dim3(512), dim3(512), 0, stream>>>(A, B, ws);
    finalize<<<dim3(1), dim3(128), 0, stream>>>(ws, labels, (float*)d_out);
}